// Round 9
// baseline (996.313 us; speedup 1.0000x reference)
//
#include <hip/hip_runtime.h>
#include <math.h>

#define T_SEQ     2048
#define HIDDEN_D  2048
#define NUM_KH    16
#define NUM_VH    32
#define HEAD_DIM  128
#define K_TOTAL   2048   // 16*128
#define V_TOTAL   4096   // 32*128
#define QKV_TOTAL 8192   // 2*K_TOTAL + V_TOTAL
#define EPS_F     1e-6f
#define CC        32     // chunk length
#define NCHUNK    (T_SEQ / CC)
#define NV        4      // v-columns per p2 block (Dv split 32 ways -> 1024 blocks)

typedef __attribute__((ext_vector_type(4))) float f32x4;
typedef __attribute__((ext_vector_type(8))) short s16x8;
typedef __attribute__((ext_vector_type(8))) unsigned short u16x8;

__device__ __forceinline__ unsigned short f2bf(float f) {
    unsigned int u = __float_as_uint(f);
    u += 0x7FFFu + ((u >> 16) & 1u);   // RNE
    return (unsigned short)(u >> 16);
}

__device__ __forceinline__ float bf2f(unsigned short h) {
    return __uint_as_float((unsigned int)h << 16);
}

// ---------------------------------------------------------------------------
// fp32 -> bf16 cast (single buffer).
// ---------------------------------------------------------------------------
__global__ __launch_bounds__(256) void cast_bf16_kernel(
    const float* __restrict__ src, unsigned short* __restrict__ dst, int n4)
{
    int idx = blockIdx.x * 256 + threadIdx.x;
    if (idx >= n4) return;
    float4 v = ((const float4*)src)[idx];
    ushort4 o;
    o.x = f2bf(v.x); o.y = f2bf(v.y); o.z = f2bf(v.z); o.w = f2bf(v.w);
    ((ushort4*)dst)[idx] = o;
}

// ---------------------------------------------------------------------------
// Fused cast of hs (1048576 f4), Wqkv (4194304 f4), Wz (2097152 f4).
// ---------------------------------------------------------------------------
__global__ __launch_bounds__(256) void cast3_kernel(
    const float* __restrict__ hs, const float* __restrict__ Wqkv,
    const float* __restrict__ Wz, unsigned short* __restrict__ hs_bf,
    unsigned short* __restrict__ Wqkv_bf, unsigned short* __restrict__ Wz_bf)
{
    int idx = blockIdx.x * 256 + threadIdx.x;          // < 7340032
    const float* src; unsigned short* dst; int off;
    if (idx < 1048576)      { src = hs;   dst = hs_bf;   off = idx; }
    else if (idx < 5242880) { src = Wqkv; dst = Wqkv_bf; off = idx - 1048576; }
    else                    { src = Wz;   dst = Wz_bf;   off = idx - 5242880; }
    float4 v = ((const float4*)src)[off];
    ushort4 o;
    o.x = f2bf(v.x); o.y = f2bf(v.y); o.z = f2bf(v.z); o.w = f2bf(v.w);
    ((ushort4*)dst)[off] = o;
}

// ---------------------------------------------------------------------------
// bf16 MFMA GEMM (NT): C[M,N] fp32 = A[M,K]bf16 * B[N,K]bf16^T.
// Bijective XCD-aware swizzle (nwg % 8 == 0 at all call sites).
// ---------------------------------------------------------------------------
__global__ __launch_bounds__(256) void gemm_bt_bf16(
    const unsigned short* __restrict__ A, const unsigned short* __restrict__ B,
    float* __restrict__ C, int M, int N, int K)
{
    __shared__ unsigned short As[128 * 64];
    __shared__ unsigned short Bs[128 * 64];
    const int tid  = threadIdx.x;
    const int wave = tid >> 6;
    const int lane = tid & 63;

    const int nx  = N >> 7;
    const int nwg = nx * (M >> 7);
    const int bid = blockIdx.y * nx + blockIdx.x;
    const int cpx = nwg >> 3;
    const int swz = (bid & 7) * cpx + (bid >> 3);
    const int m0 = (swz / nx) * 128;
    const int n0 = (swz % nx) * 128;

    const int wm = (wave >> 1) * 64;
    const int wn = (wave & 1) * 64;

    f32x4 acc[4][4];
    f32x4 zero = {0.f, 0.f, 0.f, 0.f};
#pragma unroll
    for (int i = 0; i < 4; ++i)
#pragma unroll
        for (int j = 0; j < 4; ++j) acc[i][j] = zero;

    const int srow = lane >> 3;
    const int scol = (lane & 7) * 8;
    const int rm = lane & 15;
    const int koq = (lane >> 4) * 8;

    for (int kt = 0; kt < K; kt += 64) {
#pragma unroll
        for (int l = 0; l < 4; ++l) {
            const int r0 = wave * 32 + l * 8;
            const unsigned short* ga =
                A + (size_t)(m0 + r0 + srow) * K + kt + scol;
            const unsigned short* gb =
                B + (size_t)(n0 + r0 + srow) * K + kt + scol;
            __builtin_amdgcn_global_load_lds(
                (const __attribute__((address_space(1))) void*)ga,
                (__attribute__((address_space(3))) void*)&As[r0 * 64], 16, 0, 0);
            __builtin_amdgcn_global_load_lds(
                (const __attribute__((address_space(1))) void*)gb,
                (__attribute__((address_space(3))) void*)&Bs[r0 * 64], 16, 0, 0);
        }
        __syncthreads();

#pragma unroll
        for (int ks = 0; ks < 2; ++ks) {
            const int ko = ks * 32 + koq;
            s16x8 af[4], bfr[4];
#pragma unroll
            for (int i = 0; i < 4; ++i) {
                af[i]  = *(const s16x8*)&As[(wm + i * 16 + rm) * 64 + ko];
                bfr[i] = *(const s16x8*)&Bs[(wn + i * 16 + rm) * 64 + ko];
            }
#pragma unroll
            for (int i = 0; i < 4; ++i)
#pragma unroll
                for (int j = 0; j < 4; ++j)
                    acc[i][j] = __builtin_amdgcn_mfma_f32_16x16x32_bf16(
                        af[i], bfr[j], acc[i][j], 0, 0, 0);
        }
        __syncthreads();
    }

    const int cr = (lane >> 4) * 4;
    const int ccol = lane & 15;
#pragma unroll
    for (int i = 0; i < 4; ++i)
#pragma unroll
        for (int j = 0; j < 4; ++j) {
#pragma unroll
            for (int r = 0; r < 4; ++r)
                C[(size_t)(m0 + wm + i * 16 + cr + r) * N
                  + n0 + wn + j * 16 + ccol] = acc[i][j][r];
        }
}

// ---------------------------------------------------------------------------
// fp32 tile GEMM (NT), used for the small ab projection (N=64).
// ---------------------------------------------------------------------------
__global__ __launch_bounds__(256) void gemm_nt_64(
    const float* __restrict__ A, const float* __restrict__ B,
    float* __restrict__ C, int M, int N, int K)
{
    __shared__ float As[16][68];
    __shared__ float Bs[16][68];
    const int tid = threadIdx.x;
    const int m0 = blockIdx.y * 64;
    const int n0 = blockIdx.x * 64;
    const int tm = tid >> 4;
    const int tn = tid & 15;
    const int lr = tid >> 2;
    const int lc = (tid & 3) * 4;

    float acc[4][4];
#pragma unroll
    for (int i = 0; i < 4; ++i)
#pragma unroll
        for (int j = 0; j < 4; ++j) acc[i][j] = 0.f;

    for (int kt = 0; kt < K; kt += 16) {
        float4 av = *(const float4*)(A + (size_t)(m0 + lr) * K + kt + lc);
        float4 bv = *(const float4*)(B + (size_t)(n0 + lr) * K + kt + lc);
        As[lc + 0][lr] = av.x; As[lc + 1][lr] = av.y;
        As[lc + 2][lr] = av.z; As[lc + 3][lr] = av.w;
        Bs[lc + 0][lr] = bv.x; Bs[lc + 1][lr] = bv.y;
        Bs[lc + 2][lr] = bv.z; Bs[lc + 3][lr] = bv.w;
        __syncthreads();
#pragma unroll
        for (int kk = 0; kk < 16; ++kk) {
            float4 a4 = *(const float4*)&As[kk][tm * 4];
            float4 b4 = *(const float4*)&Bs[kk][tn * 4];
            float a[4] = {a4.x, a4.y, a4.z, a4.w};
            float b[4] = {b4.x, b4.y, b4.z, b4.w};
#pragma unroll
            for (int i = 0; i < 4; ++i)
#pragma unroll
                for (int j = 0; j < 4; ++j)
                    acc[i][j] = fmaf(a[i], b[j], acc[i][j]);
        }
        __syncthreads();
    }
#pragma unroll
    for (int i = 0; i < 4; ++i) {
        float4 o = make_float4(acc[i][0], acc[i][1], acc[i][2], acc[i][3]);
        *(float4*)(C + (size_t)(m0 + tm * 4 + i) * N + n0 + tn * 4) = o;
    }
}

// ---------------------------------------------------------------------------
// Concat Wa (32x2048) and Wb (32x2048) into Wab (64x2048), float4 copies.
// ---------------------------------------------------------------------------
__global__ __launch_bounds__(256) void concat_ab_kernel(
    const float* __restrict__ Wa, const float* __restrict__ Wb,
    float* __restrict__ Wab)
{
    int idx = blockIdx.x * 256 + threadIdx.x;          // float4 index, 32768
    int half = 16384;                                  // 32*2048/4
    const float* src = (idx < half) ? Wa : Wb;
    int off = (idx < half) ? idx : idx - half;
    ((float4*)Wab)[idx] = ((const float4*)src)[off];
}

// ---------------------------------------------------------------------------
// Gating finalize.
// ---------------------------------------------------------------------------
__global__ __launch_bounds__(256) void gating_finalize_kernel(
    const float* __restrict__ ab, const float* __restrict__ A_log,
    const float* __restrict__ dt_bias, float* __restrict__ g,
    float* __restrict__ beta)
{
    int idx = blockIdx.x * 256 + threadIdx.x;          // t*32 + h
    int t = idx >> 5, h = idx & 31;
    float a = ab[t * 64 + h] + dt_bias[h];
    float b = ab[t * 64 + 32 + h];
    float sp = (a > 20.f) ? a : log1pf(expf(a));
    g[idx] = -expf(A_log[h]) * sp;
    beta[idx] = 1.f / (1.f + expf(-b));
}

// ---------------------------------------------------------------------------
// Depthwise causal conv1d (K=4) + SiLU for the V channels only.
// ---------------------------------------------------------------------------
__global__ __launch_bounds__(256) void conv_v_kernel(
    const float* __restrict__ mixed, const float* __restrict__ cw,
    float* __restrict__ vb)
{
    int idx = blockIdx.x * 256 + threadIdx.x;          // t*4096 + c
    int c = idx & (V_TOTAL - 1);
    int t = idx >> 12;
    int ch = 2 * K_TOTAL + c;
    const float4 w = *(const float4*)(cw + (size_t)ch * 4);
    const float* base = mixed + (size_t)t * QKV_TOTAL + ch;
    float y = w.w * base[0];
    if (t >= 1) y = fmaf(w.z, base[-QKV_TOTAL], y);
    if (t >= 2) y = fmaf(w.y, base[-2 * QKV_TOTAL], y);
    if (t >= 3) y = fmaf(w.x, base[-3 * QKV_TOTAL], y);
    vb[idx] = y / (1.f + expf(-y));
}

// ---------------------------------------------------------------------------
// Fused conv1d + SiLU + L2-norm for q/k channels, writing bf16 only.
// ---------------------------------------------------------------------------
__global__ __launch_bounds__(64) void convqk_l2_kernel(
    const float* __restrict__ mixed, const float* __restrict__ cw,
    unsigned short* __restrict__ qk_bf)
{
    const int row = blockIdx.x;        // t*32 + r
    const int t = row >> 5;
    const int r = row & 31;
    const int lane = threadIdx.x;
    const int c = r * HEAD_DIM + lane * 2;     // channel in [0, 4096)
    const float4 w0 = *(const float4*)(cw + (size_t)c * 4);
    const float4 w1 = *(const float4*)(cw + (size_t)(c + 1) * 4);
    const float* base = mixed + (size_t)t * QKV_TOTAL + c;
    float2 x0 = *(const float2*)base;
    float y0 = w0.w * x0.x, y1 = w1.w * x0.y;
    if (t >= 1) {
        float2 x = *(const float2*)(base - QKV_TOTAL);
        y0 = fmaf(w0.z, x.x, y0); y1 = fmaf(w1.z, x.y, y1);
    }
    if (t >= 2) {
        float2 x = *(const float2*)(base - 2 * QKV_TOTAL);
        y0 = fmaf(w0.y, x.x, y0); y1 = fmaf(w1.y, x.y, y1);
    }
    if (t >= 3) {
        float2 x = *(const float2*)(base - 3 * QKV_TOTAL);
        y0 = fmaf(w0.x, x.x, y0); y1 = fmaf(w1.x, x.y, y1);
    }
    y0 = y0 / (1.f + expf(-y0));
    y1 = y1 / (1.f + expf(-y1));
    float s = y0 * y0 + y1 * y1;
    for (int off = 32; off > 0; off >>= 1) s += __shfl_down(s, off);
    s = __shfl(s, 0);
    float inv = rsqrtf(s + EPS_F);
    unsigned short* qb = qk_bf + (size_t)t * 4096 + c;
    qb[0] = f2bf(y0 * inv);
    qb[1] = f2bf(y1 * inv);
}

// ---------------------------------------------------------------------------
// GDN phase 1 (unchanged).
// ---------------------------------------------------------------------------
__global__ __launch_bounds__(256) void gdn_p1(
    const unsigned short* __restrict__ qk_bf, const float* __restrict__ g,
    const float* __restrict__ beta, unsigned short* __restrict__ PTbuf,
    unsigned short* __restrict__ K2buf, float* __restrict__ lam_g,
    float* __restrict__ bet_g)
{
    __shared__ float Kn[CC][132];
    __shared__ float Qn[CC][132];
    __shared__ float Wm[CC][33];
    __shared__ float Tld[CC][36];
    __shared__ float Pm[CC][33];
    __shared__ float Trl[CC][33];
    __shared__ float cums[CC];
    __shared__ float betas[CC];
    __shared__ float rlS[CC];

    const int tid = threadIdx.x;
    const int h   = blockIdx.x;
    const int cix = blockIdx.y;
    const int t0  = cix * CC;
    const int kh  = h >> 1;
    const float scale = 0.08838834764831845f;
    const size_t mb = ((size_t)cix * NUM_VH + h);
    const size_t sb = mb * CC;

    if (tid < CC) {
        float x = g[(size_t)(t0 + tid) * NUM_VH + h];
        float bv = beta[(size_t)(t0 + tid) * NUM_VH + h];
#pragma unroll
        for (int off = 1; off < 32; off <<= 1) {
            float n = __shfl_up(x, off);
            if (tid >= off) x += n;
        }
        cums[tid] = x;
        betas[tid] = bv;
        float c31 = __shfl(x, 31);
        lam_g[sb + tid] = expf(x);
        bet_g[sb + tid] = bv;
        rlS[tid] = expf(c31 - x);
    }
#pragma unroll
    for (int p = 0; p < 2; ++p) {
        int idx = p * 256 + tid;            // 512 chunks of 8 elems
        int i = idx >> 4, ch = (idx & 15) * 8;
        const unsigned short* qr =
            qk_bf + (size_t)(t0 + i) * 4096 + kh * HEAD_DIM + ch;
        u16x8 q8 = *(const u16x8*)qr;
        u16x8 k8 = *(const u16x8*)(qr + K_TOTAL);
        float4 kf0, kf1, qf0, qf1;
        kf0.x = bf2f(k8[0]); kf0.y = bf2f(k8[1]);
        kf0.z = bf2f(k8[2]); kf0.w = bf2f(k8[3]);
        kf1.x = bf2f(k8[4]); kf1.y = bf2f(k8[5]);
        kf1.z = bf2f(k8[6]); kf1.w = bf2f(k8[7]);
        qf0.x = bf2f(q8[0]) * scale; qf0.y = bf2f(q8[1]) * scale;
        qf0.z = bf2f(q8[2]) * scale; qf0.w = bf2f(q8[3]) * scale;
        qf1.x = bf2f(q8[4]) * scale; qf1.y = bf2f(q8[5]) * scale;
        qf1.z = bf2f(q8[6]) * scale; qf1.w = bf2f(q8[7]) * scale;
        *(float4*)&Kn[i][ch]     = kf0;
        *(float4*)&Kn[i][ch + 4] = kf1;
        *(float4*)&Qn[i][ch]     = qf0;
        *(float4*)&Qn[i][ch + 4] = qf1;
    }
    __syncthreads();

    {
        const int i0 = (tid >> 4) * 2, j0 = (tid & 15) * 2;
        float wa[2][2] = {{0.f, 0.f}, {0.f, 0.f}};
        float pa[2][2] = {{0.f, 0.f}, {0.f, 0.f}};
        for (int k = 0; k < HEAD_DIM; k += 4) {
            float4 a0 = *(const float4*)&Kn[i0][k];
            float4 a1 = *(const float4*)&Kn[i0 + 1][k];
            float4 b0 = *(const float4*)&Kn[j0][k];
            float4 b1 = *(const float4*)&Kn[j0 + 1][k];
            float4 c0 = *(const float4*)&Qn[i0][k];
            float4 c1 = *(const float4*)&Qn[i0 + 1][k];
            const float* ap0 = (const float*)&a0;
            const float* ap1 = (const float*)&a1;
            const float* bp0 = (const float*)&b0;
            const float* bp1 = (const float*)&b1;
            const float* cp0 = (const float*)&c0;
            const float* cp1 = (const float*)&c1;
#pragma unroll
            for (int cc = 0; cc < 4; ++cc) {
                wa[0][0] = fmaf(ap0[cc], bp0[cc], wa[0][0]);
                wa[0][1] = fmaf(ap0[cc], bp1[cc], wa[0][1]);
                wa[1][0] = fmaf(ap1[cc], bp0[cc], wa[1][0]);
                wa[1][1] = fmaf(ap1[cc], bp1[cc], wa[1][1]);
                pa[0][0] = fmaf(cp0[cc], bp0[cc], pa[0][0]);
                pa[0][1] = fmaf(cp0[cc], bp1[cc], pa[0][1]);
                pa[1][0] = fmaf(cp1[cc], bp0[cc], pa[1][0]);
                pa[1][1] = fmaf(cp1[cc], bp1[cc], pa[1][1]);
            }
        }
#pragma unroll
        for (int di = 0; di < 2; ++di)
#pragma unroll
            for (int dj = 0; dj < 2; ++dj) {
                int i = i0 + di, j = j0 + dj;
                float rr = expf(fminf(cums[i] - cums[j], 0.f));
                Wm[i][j] = (j < i) ? betas[i] * rr * wa[di][dj] : 0.f;
                Pm[i][j] = (j <= i) ? rr * pa[di][dj] : 0.f;
            }
    }
    __syncthreads();

    {
        const int col = tid >> 3, tk = tid & 7;
        if (tk == 0) Tld[0][col] = (col == 0) ? 1.f : 0.f;
        for (int i = 1; i < CC; ++i) {
            float part = 0.f;
            for (int j = tk; j < i; j += 8)
                part = fmaf(Wm[i][j], Tld[j][col], part);
            part += __shfl_xor(part, 4);
            part += __shfl_xor(part, 2);
            part += __shfl_xor(part, 1);
            if (tk == 0) Tld[i][col] = ((i == col) ? 1.f : 0.f) - part;
        }
    }
    __syncthreads();

    // Trl = diag(rl) T ; PT = P @ T -> global (bf16)
    {
        const int i = tid >> 3, j0 = (tid & 7) * 4;
        const float r = rlS[i];
#pragma unroll
        for (int e = 0; e < 4; ++e)
            Trl[i][j0 + e] = Tld[i][j0 + e] * r;
        float4 accp = {0.f, 0.f, 0.f, 0.f};
        for (int m = 0; m < CC; ++m) {
            float pv = Pm[i][m];
            float4 tv = *(const float4*)&Tld[m][j0];
            accp.x = fmaf(pv, tv.x, accp.x);
            accp.y = fmaf(pv, tv.y, accp.y);
            accp.z = fmaf(pv, tv.z, accp.z);
            accp.w = fmaf(pv, tv.w, accp.w);
        }
        ushort4 pt4;
        pt4.x = f2bf(accp.x); pt4.y = f2bf(accp.y);
        pt4.z = f2bf(accp.z); pt4.w = f2bf(accp.w);
        *(ushort4*)(PTbuf + mb * (CC * CC) + tid * 4) = pt4;
    }
    __syncthreads();

    // K2[m][k] = sum_j Trl[j][m] * K[j][k]  -> bf16 global
    {
        const int m0 = tid >> 3;
        const int q  = (tid & 7) * 4;          // strided cols: q + 32*c
        float acc[4][4];
#pragma unroll
        for (int c = 0; c < 4; ++c)
#pragma unroll
            for (int e = 0; e < 4; ++e) acc[c][e] = 0.f;
        for (int j = 0; j < CC; ++j) {
            float t = Trl[j][m0];
#pragma unroll
            for (int c = 0; c < 4; ++c) {
                float4 a = *(const float4*)&Kn[j][q + 32 * c];
                acc[c][0] = fmaf(t, a.x, acc[c][0]);
                acc[c][1] = fmaf(t, a.y, acc[c][1]);
                acc[c][2] = fmaf(t, a.z, acc[c][2]);
                acc[c][3] = fmaf(t, a.w, acc[c][3]);
            }
        }
        unsigned short* kout =
            K2buf + mb * (CC * HEAD_DIM) + m0 * HEAD_DIM + q;
#pragma unroll
        for (int c = 0; c < 4; ++c) {
            ushort4 o4;
            o4.x = f2bf(acc[c][0]); o4.y = f2bf(acc[c][1]);
            o4.z = f2bf(acc[c][2]); o4.w = f2bf(acc[c][3]);
            *(ushort4*)(kout + 32 * c) = o4;
        }
    }
}

// ---------------------------------------------------------------------------
// GDN phase 2 (NV=4: 1024 blocks, 4/CU co-resident; LDS 36608 B).
// Same verified 2-barrier schedule; PTl/lamS dropped from LDS (per-thread
// L2-hot global loads issued at phase-1 top, consumed in phase 2).
// Mapping: ri=tid>>3 (row), hh4=(tid>>1)&3 (4-way k-split, logical chunks
// c=4j+hh4), rn=(tid&1)*2 (col pair of NV=4).
// ALIGNMENT (r8 crash fix): Sm/Dl stride = 6 floats (24 B) so every
// float2 access (stride*row + rn)*4 is 8B-aligned. Stride 5 (20 B) was
// 4B-aligned on odd rows -> misaligned ds_read_b64 -> fault.
// Per-half-wave bank audits (32 lanes: ri 0..3 x hh4 0..3 x rn {0,2}):
//  - Kn/Qn b128: c=4j+hh4 under swizzle key ri&3 -> 8 chunk slots covered,
//    2 rows per slot = 2-way (free, m136).
//  - Sm ph1 read, stride 6: 48c+6c8+rn -> 8 distinct addrs, 2/bank = 2-way.
//  - O-loop Dl[8*hh4+jj][rn]: 48*hh4+rn mod 32 = {0,2,16,18}x2 -> 2-way.
//  - state K2l b32 word sk -> banks distinct.
//  - state Sm words 12*sk+sn -> 32 distinct banks.
// ---------------------------------------------------------------------------
__global__ __launch_bounds__(256, 4) void gdn_p2(
    const float* __restrict__ vb, const unsigned short* __restrict__ qk_bf,
    const unsigned short* __restrict__ PTbuf,
    const unsigned short* __restrict__ K2buf, const float* __restrict__ lam_g,
    const float* __restrict__ bet_g, float* __restrict__ o)
{
    __shared__ unsigned short Kn[CC][128];        // 8192
    __shared__ unsigned short Qn[CC][128];        // 8192
    __shared__ unsigned short K2l[2][CC][128];    // 16384
    __shared__ float Sm[HEAD_DIM][6];             // 3072
    __shared__ float Dl[CC][6];                   // 768

    const int tid = threadIdx.x;
    const int wv  = tid >> 6;
    const int ln  = tid & 63;
    const int h   = blockIdx.x >> 5;
    const int V0  = (blockIdx.x & 31) * NV;
    const int kh  = h >> 1;
    const float scale = 0.08838834764831845f;

    const int ri  = tid >> 3;            // row 0..31
    const int hh4 = (tid >> 1) & 3;      // k-quarter (interleaved chunks)
    const int rn  = (tid & 1) * 2;       // col pair within NV=4
    const int rx  = ri & 3;              // swizzle key

    const int sk = tid >> 2;             // state: k-rows 2sk, 2sk+1
    const int sn = tid & 3;              // state: 1 col

    // DMA lane geometry (bf16 rows, 256B): 4 rows per wave-instr.
    const int drow = ln >> 4;            // row within 4-row group
    const int dc   = ln & 15;            // 16B chunk within row

#define DMA_KQ(T0)                                                            \
    {                                                                         \
        _Pragma("unroll")                                                     \
        for (int p = 0; p < 2; ++p) {                                         \
            const int i = p * 16 + wv * 4 + drow;                             \
            const int sc = 2 * ((dc >> 1) ^ (i & 3)) + (dc & 1);              \
            const unsigned short* sq = qk_bf + (size_t)((T0) + i) * 4096      \
                                       + kh * HEAD_DIM + sc * 8;              \
            __builtin_amdgcn_global_load_lds(                                 \
                (const __attribute__((address_space(1))) void*)(sq + K_TOTAL),\
                (__attribute__((address_space(3))) void*)                     \
                    &Kn[p * 16 + wv * 4][0], 16, 0, 0);                       \
            __builtin_amdgcn_global_load_lds(                                 \
                (const __attribute__((address_space(1))) void*)sq,            \
                (__attribute__((address_space(3))) void*)                     \
                    &Qn[p * 16 + wv * 4][0], 16, 0, 0);                       \
        }                                                                     \
    }

#define DMA_K2(MB, BUF)                                                       \
    {                                                                         \
        _Pragma("unroll")                                                     \
        for (int p = 0; p < 2; ++p) {                                         \
            const unsigned short* sk2 = K2buf + (MB) * (CC * HEAD_DIM)        \
                                        + p * 2048 + wv * 512 + ln * 8;       \
            __builtin_amdgcn_global_load_lds(                                 \
                (const __attribute__((address_space(1))) void*)sk2,           \
                (__attribute__((address_space(3))) void*)                     \
                    &K2l[BUF][p * 16 + wv * 4][0], 16, 0, 0);                 \
        }                                                                     \
    }

    Sm[2 * sk][sn] = 0.f;
    Sm[2 * sk + 1][sn] = 0.f;

    // ---- prologue: chunk 0 ----
    DMA_KQ(0);
    DMA_K2((size_t)h, 0);
    float2 vR = *(const float2*)(vb + (size_t)ri * V_TOTAL
                                 + h * HEAD_DIM + V0 + rn);

    int cur = 0;
    for (int cix = 0; cix < NCHUNK; ++cix) {
        const int t0 = cix * CC;
        const size_t mb = (size_t)cix * NUM_VH + h;
        __syncthreads();                       // bar A (drains DMAs)

        // L2-hot scalar/vector loads for this chunk (consumed below / phase2)
        const float lam  = lam_g[mb * CC + ri];
        const float bet  = bet_g[mb * CC + ri];
        const float lamL = lam_g[mb * CC + CC - 1];
        u16x8 pt = *(const u16x8*)(PTbuf + mb * (CC * CC) + ri * CC + hh4 * 8);

        // ---- phase 1: r1/r2 (4-way k-split) ----
        float r1x = 0.f, r1y = 0.f, r2x = 0.f, r2y = 0.f;
#pragma unroll
        for (int j = 0; j < 4; ++j) {
            const int c  = 4 * j + hh4;                        // logical chunk
            const int pc = (2 * ((c >> 1) ^ rx) + (c & 1)) * 8;
            u16x8 kv = *(const u16x8*)&Kn[ri][pc];
            u16x8 qv = *(const u16x8*)&Qn[ri][pc];
            const int kb = c * 8;
#pragma unroll
            for (int c8 = 0; c8 < 8; ++c8) {
                float kf = bf2f(kv[c8]);
                float qf = bf2f(qv[c8]);
                float2 s = *(const float2*)&Sm[kb + c8][rn];
                r1x = fmaf(kf, s.x, r1x);
                r1y = fmaf(kf, s.y, r1y);
                r2x = fmaf(qf, s.x, r2x);
                r2y = fmaf(qf, s.y, r2y);
            }
        }
        // reduce over hh4 (tid bits 1,2)
        r1x += __shfl_xor(r1x, 2); r1x += __shfl_xor(r1x, 4);
        r1y += __shfl_xor(r1y, 2); r1y += __shfl_xor(r1y, 4);
        r2x += __shfl_xor(r2x, 2); r2x += __shfl_xor(r2x, 4);
        r2y += __shfl_xor(r2y, 2); r2y += __shfl_xor(r2y, 4);
        {
            float dlx = bet * (vR.x - lam * r1x);
            float dly = bet * (vR.y - lam * r1y);
            if (hh4 == 0) { Dl[ri][rn] = dlx; Dl[ri][rn + 1] = dly; }
        }
        const float lsc = lam * scale;
        float ox = r2x * lsc, oy = r2y * lsc;
        __syncthreads();                       // bar C (Dl visible; Kn/Qn dead)

        // ---- phase 2 ----
        const int nxt = cur ^ 1;
        float2 vN;
        const int more = (cix + 1 < NCHUNK);
        if (more) {
            const int t0n = t0 + CC;
            const size_t mbn = mb + NUM_VH;
            DMA_KQ(t0n);
            DMA_K2(mbn, nxt);
            vN = *(const float2*)(vb + (size_t)(t0n + ri) * V_TOTAL
                                  + h * HEAD_DIM + V0 + rn);
        }

        // O = lam*scale*r2 + PT @ Dl  (j-loop split 4 ways over hh4)
        {
            float pox = 0.f, poy = 0.f;
#pragma unroll
            for (int jj = 0; jj < 8; ++jj) {
                const int j = hh4 * 8 + jj;
                float p = bf2f(pt[jj]);
                float2 d = *(const float2*)&Dl[j][rn];
                pox = fmaf(p, d.x, pox);
                poy = fmaf(p, d.y, poy);
            }
            pox += __shfl_xor(pox, 2); pox += __shfl_xor(pox, 4);
            poy += __shfl_xor(poy, 2); poy += __shfl_xor(poy, 4);
            ox += pox; oy += poy;
            if (hh4 == 0)
                *(float2*)(o + (size_t)(t0 + ri) * V_TOTAL + h * HEAD_DIM + V0 + rn)
                    = make_float2(ox, oy);
        }

        // S = lamL*S + K2^T @ Dl  (2 k-rows x 1 col per thread)
        {
            float s0 = lamL * Sm[2 * sk][sn];
            float s1 = lamL * Sm[2 * sk + 1][sn];
            for (int j = 0; j < CC; ++j) {
                unsigned int kk2 =
                    *(const unsigned int*)&K2l[cur][j][2 * sk];
                float d = Dl[j][sn];
                s0 = fmaf(bf2f((unsigned short)(kk2 & 0xffffu)), d, s0);
                s1 = fmaf(bf2f((unsigned short)(kk2 >> 16)), d, s1);
            }
            Sm[2 * sk][sn] = s0;
            Sm[2 * sk + 1][sn] = s1;
        }

        if (more) vR = vN;
        cur = nxt;
    }
#undef DMA_KQ
#undef DMA_K2
}

// ---------------------------------------------------------------------------
// Gated RMSNorm, fused with bf16 output cast (writes ob_bf directly).
// ---------------------------------------------------------------------------
__global__ __launch_bounds__(64) void rmsnorm_gate_kernel(
    const float* __restrict__ o, const float* __restrict__ z,
    const float* __restrict__ nw, unsigned short* __restrict__ ob_bf)
{
    const int row = blockIdx.x;
    const float* p = o + (size_t)row * HEAD_DIM;
    const float* zp = z + (size_t)row * HEAD_DIM;
    const int lane = threadIdx.x;
    float2 v = *(const float2*)(p + lane * 2);
    float s = v.x * v.x + v.y * v.y;
    for (int off = 32; off > 0; off >>= 1) s += __shfl_down(s, off);
    s = __shfl(s, 0);
    float inv = rsqrtf(s * (1.f / HEAD_DIM) + EPS_F);
    float2 zv = *(const float2*)(zp + lane * 2);
    float2 wv = *(const float2*)(nw + lane * 2);
    v.x = v.x * inv * wv.x * (zv.x / (1.f + expf(-zv.x)));
    v.y = v.y * inv * wv.y * (zv.y / (1.f + expf(-zv.y)));
    unsigned short* q = ob_bf + (size_t)row * HEAD_DIM + lane * 2;
    q[0] = f2bf(v.x);
    q[1] = f2bf(v.y);
}

// ---------------------------------------------------------------------------
// Workspace layout (floats), audited against launch order:
//   mixed  [0, 16777216)           QKV GEMM out; dead after conv_v/convqk_l2
//   ob     [0, 8388608)            p2 output (mixed dead by then)
//   PTbuf  [8388608, 9437184)      bf16, p1 out; dead after p2
//   ob_bf  [8388608, 9437184)      rmsnorm out (PTbuf dead)
//   K2buf  [9437184, 13631488)     bf16; dead after p2
//   lam_b  [13631488, 13697024), bet_b [13697024, 13762560)
//   vb     [16777216, 25165824)    conv_v out (overwrites hs_bf/Wqkv_bf)
//   qk_bf  [25165824, 29360128)    convqk_l2 out (Wz_bf dead by then)
//   Wz_bf  [27262976, 31457280)    dead after z GEMM
//   Wab    [27262976, 27394048), ab [27394048, 27525120)  (dead early)
//   zb     [33554432, 41943040)    live until rmsnorm
//   Wout_bf[37748736, 41943040)    written after rmsnorm (overlaps zb)
//   gb     [41943040, 42008576), bb [42008576, 42074112)
// ---------------------------------------------------------------------------
extern "C" void kernel_launch(void* const* d_in, const int* in_sizes, int n_in,
                              void* d_out, int out_size, void* d_ws,
                              size_t ws_size, hipStream_t stream)
{
    const float* hs    = (const float*)d_in[0];
    const float* Wqkv  = (const float*)d_in[1];
    const float* Wz    = (const float*)d_in[2];
    const float* Wa    = (const float*)d_in[3];
    const float* Wb    = (const float*)d_in[4];
    const float* cw    = (const float*)d_in[5];
    const float* Wout  = (const float*)d_in[6];
    const float* nw    = (const float*)d_in[7];
    const float* A_log = (const float*)d_in[8];
    const float* dtb   = (const float*)d_in[9];
    float* out = (float*)d_out;

    float* F     = (float*)d_ws;
    float* mixed = F;
    float* ob    = F;
    unsigned short* PTbuf = (unsigned short*)(F + (size_t)8388608);
    unsigned short* ob_bf = (unsigned short*)(F + (size_t)8388608);
    unsigned short* K2buf = (unsigned short*)(F + (size_t)9437184);
    float* lam_b = F + (size_t)13631488;
    float* bet_b = F + (size_t)13697024;
    unsigned short* hs_bf   = (unsigned short*)(F + (size_t)16777216);
    unsigned short* Wqkv_bf = (unsigned short*)(F + (size_t)18874368);
    float* vb = F + (size_t)16777216;
    unsigned short* qk_bf = (unsigned short*)(F + (size_t)25165824);
    unsigned short* Wz_bf   = (unsigned short*)(F + (size_t)27262976);
    float* Wab = F + (size_t)27262976;
    float* ab  = F + (size_t)27394048;
    float* zb  = F + (size_t)33554432;
    unsigned short* Wout_bf = (unsigned short*)(F + (size_t)37748736);
    float* gb = F + (size_t)41943040;
    float* bb = F + (size_t)42008576;

    cast3_kernel<<<7340032 / 256, 256, 0, stream>>>(
        hs, Wqkv, Wz, hs_bf, Wqkv_bf, Wz_bf);
    gemm_bt_bf16<<<dim3(QKV_TOTAL / 128, T_SEQ / 128), 256, 0, stream>>>(
        hs_bf, Wqkv_bf, mixed, T_SEQ, QKV_TOTAL, HIDDEN_D);
    gemm_bt_bf16<<<dim3(V_TOTAL / 128, T_SEQ / 128), 256, 0, stream>>>(
        hs_bf, Wz_bf, zb, T_SEQ, V_TOTAL, HIDDEN_D);
    concat_ab_kernel<<<32768 / 256, 256, 0, stream>>>(Wa, Wb, Wab);
    gemm_nt_64<<<dim3(1, T_SEQ / 64), 256, 0, stream>>>(
        hs, Wab, ab, T_SEQ, 64, HIDDEN_D);
    gating_finalize_kernel<<<(T_SEQ * NUM_VH) / 256, 256, 0, stream>>>(
        ab, A_log, dtb, gb, bb);
    conv_v_kernel<<<(T_SEQ * V_TOTAL) / 256, 256, 0, stream>>>(
        mixed, cw, vb);
    convqk_l2_kernel<<<T_SEQ * 32, 64, 0, stream>>>(mixed, cw, qk_bf);
    gdn_p1<<<dim3(NUM_VH, NCHUNK), 256, 0, stream>>>(
        qk_bf, gb, bb, PTbuf, K2buf, lam_b, bet_b);
    gdn_p2<<<NUM_VH * (HEAD_DIM / NV), 256, 0, stream>>>(
        vb, qk_bf, PTbuf, K2buf, lam_b, bet_b, ob);
    rmsnorm_gate_kernel<<<T_SEQ * NUM_VH, 64, 0, stream>>>(ob, zb, nw, ob_bf);
    cast_bf16_kernel<<<2097152 / 256, 256, 0, stream>>>(Wout, Wout_bf, 2097152);
    gemm_bt_bf16<<<dim3(HIDDEN_D / 128, T_SEQ / 128), 256, 0, stream>>>(
        ob_bf, Wout_bf, out, T_SEQ, HIDDEN_D, V_TOTAL);
}

// Round 10
// 896.424 us; speedup vs baseline: 1.1114x; 1.1114x over previous
//
#include <hip/hip_runtime.h>
#include <math.h>

#define T_SEQ     2048
#define HIDDEN_D  2048
#define NUM_KH    16
#define NUM_VH    32
#define HEAD_DIM  128
#define K_TOTAL   2048   // 16*128
#define V_TOTAL   4096   // 32*128
#define QKV_TOTAL 8192   // 2*K_TOTAL + V_TOTAL
#define EPS_F     1e-6f
#define CC        32     // chunk length
#define NCHUNK    (T_SEQ / CC)
#define NV        8      // v-columns per p2 block (Dv split 16 ways -> 512 blocks)

typedef __attribute__((ext_vector_type(4))) float f32x4;
typedef __attribute__((ext_vector_type(8))) short s16x8;
typedef __attribute__((ext_vector_type(8))) unsigned short u16x8;

__device__ __forceinline__ unsigned short f2bf(float f) {
    unsigned int u = __float_as_uint(f);
    u += 0x7FFFu + ((u >> 16) & 1u);   // RNE
    return (unsigned short)(u >> 16);
}

__device__ __forceinline__ float bf2f(unsigned short h) {
    return __uint_as_float((unsigned int)h << 16);
}

// ---------------------------------------------------------------------------
// fp32 -> bf16 cast (single buffer).
// ---------------------------------------------------------------------------
__global__ __launch_bounds__(256) void cast_bf16_kernel(
    const float* __restrict__ src, unsigned short* __restrict__ dst, int n4)
{
    int idx = blockIdx.x * 256 + threadIdx.x;
    if (idx >= n4) return;
    float4 v = ((const float4*)src)[idx];
    ushort4 o;
    o.x = f2bf(v.x); o.y = f2bf(v.y); o.z = f2bf(v.z); o.w = f2bf(v.w);
    ((ushort4*)dst)[idx] = o;
}

// ---------------------------------------------------------------------------
// Fused cast of hs (1048576 f4), Wqkv (4194304 f4), Wz (2097152 f4).
// ---------------------------------------------------------------------------
__global__ __launch_bounds__(256) void cast3_kernel(
    const float* __restrict__ hs, const float* __restrict__ Wqkv,
    const float* __restrict__ Wz, unsigned short* __restrict__ hs_bf,
    unsigned short* __restrict__ Wqkv_bf, unsigned short* __restrict__ Wz_bf)
{
    int idx = blockIdx.x * 256 + threadIdx.x;          // < 7340032
    const float* src; unsigned short* dst; int off;
    if (idx < 1048576)      { src = hs;   dst = hs_bf;   off = idx; }
    else if (idx < 5242880) { src = Wqkv; dst = Wqkv_bf; off = idx - 1048576; }
    else                    { src = Wz;   dst = Wz_bf;   off = idx - 5242880; }
    float4 v = ((const float4*)src)[off];
    ushort4 o;
    o.x = f2bf(v.x); o.y = f2bf(v.y); o.z = f2bf(v.z); o.w = f2bf(v.w);
    ((ushort4*)dst)[off] = o;
}

// ---------------------------------------------------------------------------
// bf16 MFMA GEMM (NT), fp32 out: C[M,N] = A[M,K]bf16 * B[N,K]bf16^T.
// Bijective XCD-aware swizzle (nwg % 8 == 0 at all call sites).
// ---------------------------------------------------------------------------
__global__ __launch_bounds__(256) void gemm_bt_bf16(
    const unsigned short* __restrict__ A, const unsigned short* __restrict__ B,
    float* __restrict__ C, int M, int N, int K)
{
    __shared__ unsigned short As[128 * 64];
    __shared__ unsigned short Bs[128 * 64];
    const int tid  = threadIdx.x;
    const int wave = tid >> 6;
    const int lane = tid & 63;

    const int nx  = N >> 7;
    const int nwg = nx * (M >> 7);
    const int bid = blockIdx.y * nx + blockIdx.x;
    const int cpx = nwg >> 3;
    const int swz = (bid & 7) * cpx + (bid >> 3);
    const int m0 = (swz / nx) * 128;
    const int n0 = (swz % nx) * 128;

    const int wm = (wave >> 1) * 64;
    const int wn = (wave & 1) * 64;

    f32x4 acc[4][4];
    f32x4 zero = {0.f, 0.f, 0.f, 0.f};
#pragma unroll
    for (int i = 0; i < 4; ++i)
#pragma unroll
        for (int j = 0; j < 4; ++j) acc[i][j] = zero;

    const int srow = lane >> 3;
    const int scol = (lane & 7) * 8;
    const int rm = lane & 15;
    const int koq = (lane >> 4) * 8;

    for (int kt = 0; kt < K; kt += 64) {
#pragma unroll
        for (int l = 0; l < 4; ++l) {
            const int r0 = wave * 32 + l * 8;
            const unsigned short* ga =
                A + (size_t)(m0 + r0 + srow) * K + kt + scol;
            const unsigned short* gb =
                B + (size_t)(n0 + r0 + srow) * K + kt + scol;
            __builtin_amdgcn_global_load_lds(
                (const __attribute__((address_space(1))) void*)ga,
                (__attribute__((address_space(3))) void*)&As[r0 * 64], 16, 0, 0);
            __builtin_amdgcn_global_load_lds(
                (const __attribute__((address_space(1))) void*)gb,
                (__attribute__((address_space(3))) void*)&Bs[r0 * 64], 16, 0, 0);
        }
        __syncthreads();

#pragma unroll
        for (int ks = 0; ks < 2; ++ks) {
            const int ko = ks * 32 + koq;
            s16x8 af[4], bfr[4];
#pragma unroll
            for (int i = 0; i < 4; ++i) {
                af[i]  = *(const s16x8*)&As[(wm + i * 16 + rm) * 64 + ko];
                bfr[i] = *(const s16x8*)&Bs[(wn + i * 16 + rm) * 64 + ko];
            }
#pragma unroll
            for (int i = 0; i < 4; ++i)
#pragma unroll
                for (int j = 0; j < 4; ++j)
                    acc[i][j] = __builtin_amdgcn_mfma_f32_16x16x32_bf16(
                        af[i], bfr[j], acc[i][j], 0, 0, 0);
        }
        __syncthreads();
    }

    const int cr = (lane >> 4) * 4;
    const int ccol = lane & 15;
#pragma unroll
    for (int i = 0; i < 4; ++i)
#pragma unroll
        for (int j = 0; j < 4; ++j) {
#pragma unroll
            for (int r = 0; r < 4; ++r)
                C[(size_t)(m0 + wm + i * 16 + cr + r) * N
                  + n0 + wn + j * 16 + ccol] = acc[i][j][r];
        }
}

// ---------------------------------------------------------------------------
// Same GEMM but bf16 output (used for the QKV projection -> mixed_bf).
// ---------------------------------------------------------------------------
__global__ __launch_bounds__(256) void gemm_bt_bf16_o16(
    const unsigned short* __restrict__ A, const unsigned short* __restrict__ B,
    unsigned short* __restrict__ C, int M, int N, int K)
{
    __shared__ unsigned short As[128 * 64];
    __shared__ unsigned short Bs[128 * 64];
    const int tid  = threadIdx.x;
    const int wave = tid >> 6;
    const int lane = tid & 63;

    const int nx  = N >> 7;
    const int nwg = nx * (M >> 7);
    const int bid = blockIdx.y * nx + blockIdx.x;
    const int cpx = nwg >> 3;
    const int swz = (bid & 7) * cpx + (bid >> 3);
    const int m0 = (swz / nx) * 128;
    const int n0 = (swz % nx) * 128;

    const int wm = (wave >> 1) * 64;
    const int wn = (wave & 1) * 64;

    f32x4 acc[4][4];
    f32x4 zero = {0.f, 0.f, 0.f, 0.f};
#pragma unroll
    for (int i = 0; i < 4; ++i)
#pragma unroll
        for (int j = 0; j < 4; ++j) acc[i][j] = zero;

    const int srow = lane >> 3;
    const int scol = (lane & 7) * 8;
    const int rm = lane & 15;
    const int koq = (lane >> 4) * 8;

    for (int kt = 0; kt < K; kt += 64) {
#pragma unroll
        for (int l = 0; l < 4; ++l) {
            const int r0 = wave * 32 + l * 8;
            const unsigned short* ga =
                A + (size_t)(m0 + r0 + srow) * K + kt + scol;
            const unsigned short* gb =
                B + (size_t)(n0 + r0 + srow) * K + kt + scol;
            __builtin_amdgcn_global_load_lds(
                (const __attribute__((address_space(1))) void*)ga,
                (__attribute__((address_space(3))) void*)&As[r0 * 64], 16, 0, 0);
            __builtin_amdgcn_global_load_lds(
                (const __attribute__((address_space(1))) void*)gb,
                (__attribute__((address_space(3))) void*)&Bs[r0 * 64], 16, 0, 0);
        }
        __syncthreads();

#pragma unroll
        for (int ks = 0; ks < 2; ++ks) {
            const int ko = ks * 32 + koq;
            s16x8 af[4], bfr[4];
#pragma unroll
            for (int i = 0; i < 4; ++i) {
                af[i]  = *(const s16x8*)&As[(wm + i * 16 + rm) * 64 + ko];
                bfr[i] = *(const s16x8*)&Bs[(wn + i * 16 + rm) * 64 + ko];
            }
#pragma unroll
            for (int i = 0; i < 4; ++i)
#pragma unroll
                for (int j = 0; j < 4; ++j)
                    acc[i][j] = __builtin_amdgcn_mfma_f32_16x16x32_bf16(
                        af[i], bfr[j], acc[i][j], 0, 0, 0);
        }
        __syncthreads();
    }

    const int cr = (lane >> 4) * 4;
    const int ccol = lane & 15;
#pragma unroll
    for (int i = 0; i < 4; ++i)
#pragma unroll
        for (int j = 0; j < 4; ++j) {
#pragma unroll
            for (int r = 0; r < 4; ++r)
                C[(size_t)(m0 + wm + i * 16 + cr + r) * N
                  + n0 + wn + j * 16 + ccol] = f2bf(acc[i][j][r]);
        }
}

// ---------------------------------------------------------------------------
// fp32 tile GEMM (NT), used for the small ab projection (N=64).
// ---------------------------------------------------------------------------
__global__ __launch_bounds__(256) void gemm_nt_64(
    const float* __restrict__ A, const float* __restrict__ B,
    float* __restrict__ C, int M, int N, int K)
{
    __shared__ float As[16][68];
    __shared__ float Bs[16][68];
    const int tid = threadIdx.x;
    const int m0 = blockIdx.y * 64;
    const int n0 = blockIdx.x * 64;
    const int tm = tid >> 4;
    const int tn = tid & 15;
    const int lr = tid >> 2;
    const int lc = (tid & 3) * 4;

    float acc[4][4];
#pragma unroll
    for (int i = 0; i < 4; ++i)
#pragma unroll
        for (int j = 0; j < 4; ++j) acc[i][j] = 0.f;

    for (int kt = 0; kt < K; kt += 16) {
        float4 av = *(const float4*)(A + (size_t)(m0 + lr) * K + kt + lc);
        float4 bv = *(const float4*)(B + (size_t)(n0 + lr) * K + kt + lc);
        As[lc + 0][lr] = av.x; As[lc + 1][lr] = av.y;
        As[lc + 2][lr] = av.z; As[lc + 3][lr] = av.w;
        Bs[lc + 0][lr] = bv.x; Bs[lc + 1][lr] = bv.y;
        Bs[lc + 2][lr] = bv.z; Bs[lc + 3][lr] = bv.w;
        __syncthreads();
#pragma unroll
        for (int kk = 0; kk < 16; ++kk) {
            float4 a4 = *(const float4*)&As[kk][tm * 4];
            float4 b4 = *(const float4*)&Bs[kk][tn * 4];
            float a[4] = {a4.x, a4.y, a4.z, a4.w};
            float b[4] = {b4.x, b4.y, b4.z, b4.w};
#pragma unroll
            for (int i = 0; i < 4; ++i)
#pragma unroll
                for (int j = 0; j < 4; ++j)
                    acc[i][j] = fmaf(a[i], b[j], acc[i][j]);
        }
        __syncthreads();
    }
#pragma unroll
    for (int i = 0; i < 4; ++i) {
        float4 o = make_float4(acc[i][0], acc[i][1], acc[i][2], acc[i][3]);
        *(float4*)(C + (size_t)(m0 + tm * 4 + i) * N + n0 + tn * 4) = o;
    }
}

// ---------------------------------------------------------------------------
// Concat Wa (32x2048) and Wb (32x2048) into Wab (64x2048), float4 copies.
// ---------------------------------------------------------------------------
__global__ __launch_bounds__(256) void concat_ab_kernel(
    const float* __restrict__ Wa, const float* __restrict__ Wb,
    float* __restrict__ Wab)
{
    int idx = blockIdx.x * 256 + threadIdx.x;          // float4 index, 32768
    int half = 16384;                                  // 32*2048/4
    const float* src = (idx < half) ? Wa : Wb;
    int off = (idx < half) ? idx : idx - half;
    ((float4*)Wab)[idx] = ((const float4*)src)[off];
}

// ---------------------------------------------------------------------------
// Gating finalize.
// ---------------------------------------------------------------------------
__global__ __launch_bounds__(256) void gating_finalize_kernel(
    const float* __restrict__ ab, const float* __restrict__ A_log,
    const float* __restrict__ dt_bias, float* __restrict__ g,
    float* __restrict__ beta)
{
    int idx = blockIdx.x * 256 + threadIdx.x;          // t*32 + h
    int t = idx >> 5, h = idx & 31;
    float a = ab[t * 64 + h] + dt_bias[h];
    float b = ab[t * 64 + 32 + h];
    float sp = (a > 20.f) ? a : log1pf(expf(a));
    g[idx] = -expf(A_log[h]) * sp;
    beta[idx] = 1.f / (1.f + expf(-b));
}

// ---------------------------------------------------------------------------
// Depthwise causal conv1d (K=4) + SiLU for the V channels, bf16 mixed input.
// ---------------------------------------------------------------------------
__global__ __launch_bounds__(256) void conv_v_kernel(
    const unsigned short* __restrict__ mixed_bf, const float* __restrict__ cw,
    float* __restrict__ vb)
{
    int idx = blockIdx.x * 256 + threadIdx.x;          // t*4096 + c
    int c = idx & (V_TOTAL - 1);
    int t = idx >> 12;
    int ch = 2 * K_TOTAL + c;
    const float4 w = *(const float4*)(cw + (size_t)ch * 4);
    const unsigned short* base = mixed_bf + (size_t)t * QKV_TOTAL + ch;
    float y = w.w * bf2f(base[0]);
    if (t >= 1) y = fmaf(w.z, bf2f(base[-QKV_TOTAL]), y);
    if (t >= 2) y = fmaf(w.y, bf2f(base[-2 * QKV_TOTAL]), y);
    if (t >= 3) y = fmaf(w.x, bf2f(base[-3 * QKV_TOTAL]), y);
    vb[idx] = y / (1.f + expf(-y));
}

// ---------------------------------------------------------------------------
// Fused conv1d + SiLU + L2-norm for q/k channels (bf16 in), bf16 out.
// ---------------------------------------------------------------------------
__global__ __launch_bounds__(64) void convqk_l2_kernel(
    const unsigned short* __restrict__ mixed_bf, const float* __restrict__ cw,
    unsigned short* __restrict__ qk_bf)
{
    const int row = blockIdx.x;        // t*32 + r
    const int t = row >> 5;
    const int r = row & 31;
    const int lane = threadIdx.x;
    const int c = r * HEAD_DIM + lane * 2;     // channel in [0, 4096)
    const float4 w0 = *(const float4*)(cw + (size_t)c * 4);
    const float4 w1 = *(const float4*)(cw + (size_t)(c + 1) * 4);
    const unsigned short* base = mixed_bf + (size_t)t * QKV_TOTAL + c;
    unsigned int u0 = *(const unsigned int*)base;
    float y0 = w0.w * bf2f((unsigned short)(u0 & 0xffffu));
    float y1 = w1.w * bf2f((unsigned short)(u0 >> 16));
    if (t >= 1) {
        unsigned int u = *(const unsigned int*)(base - QKV_TOTAL);
        y0 = fmaf(w0.z, bf2f((unsigned short)(u & 0xffffu)), y0);
        y1 = fmaf(w1.z, bf2f((unsigned short)(u >> 16)), y1);
    }
    if (t >= 2) {
        unsigned int u = *(const unsigned int*)(base - 2 * QKV_TOTAL);
        y0 = fmaf(w0.y, bf2f((unsigned short)(u & 0xffffu)), y0);
        y1 = fmaf(w1.y, bf2f((unsigned short)(u >> 16)), y1);
    }
    if (t >= 3) {
        unsigned int u = *(const unsigned int*)(base - 3 * QKV_TOTAL);
        y0 = fmaf(w0.x, bf2f((unsigned short)(u & 0xffffu)), y0);
        y1 = fmaf(w1.x, bf2f((unsigned short)(u >> 16)), y1);
    }
    y0 = y0 / (1.f + expf(-y0));
    y1 = y1 / (1.f + expf(-y1));
    float s = y0 * y0 + y1 * y1;
    for (int off = 32; off > 0; off >>= 1) s += __shfl_down(s, off);
    s = __shfl(s, 0);
    float inv = rsqrtf(s + EPS_F);
    unsigned short* qb = qk_bf + (size_t)t * 4096 + c;
    qb[0] = f2bf(y0 * inv);
    qb[1] = f2bf(y1 * inv);
}

// ---------------------------------------------------------------------------
// GDN phase 1 (unchanged from r7).
// ---------------------------------------------------------------------------
__global__ __launch_bounds__(256) void gdn_p1(
    const unsigned short* __restrict__ qk_bf, const float* __restrict__ g,
    const float* __restrict__ beta, unsigned short* __restrict__ PTbuf,
    unsigned short* __restrict__ K2buf, float* __restrict__ lam_g,
    float* __restrict__ bet_g)
{
    __shared__ float Kn[CC][132];
    __shared__ float Qn[CC][132];
    __shared__ float Wm[CC][33];
    __shared__ float Tld[CC][36];
    __shared__ float Pm[CC][33];
    __shared__ float Trl[CC][33];
    __shared__ float cums[CC];
    __shared__ float betas[CC];
    __shared__ float rlS[CC];

    const int tid = threadIdx.x;
    const int h   = blockIdx.x;
    const int cix = blockIdx.y;
    const int t0  = cix * CC;
    const int kh  = h >> 1;
    const float scale = 0.08838834764831845f;
    const size_t mb = ((size_t)cix * NUM_VH + h);
    const size_t sb = mb * CC;

    if (tid < CC) {
        float x = g[(size_t)(t0 + tid) * NUM_VH + h];
        float bv = beta[(size_t)(t0 + tid) * NUM_VH + h];
#pragma unroll
        for (int off = 1; off < 32; off <<= 1) {
            float n = __shfl_up(x, off);
            if (tid >= off) x += n;
        }
        cums[tid] = x;
        betas[tid] = bv;
        float c31 = __shfl(x, 31);
        lam_g[sb + tid] = expf(x);
        bet_g[sb + tid] = bv;
        rlS[tid] = expf(c31 - x);
    }
#pragma unroll
    for (int p = 0; p < 2; ++p) {
        int idx = p * 256 + tid;            // 512 chunks of 8 elems
        int i = idx >> 4, ch = (idx & 15) * 8;
        const unsigned short* qr =
            qk_bf + (size_t)(t0 + i) * 4096 + kh * HEAD_DIM + ch;
        u16x8 q8 = *(const u16x8*)qr;
        u16x8 k8 = *(const u16x8*)(qr + K_TOTAL);
        float4 kf0, kf1, qf0, qf1;
        kf0.x = bf2f(k8[0]); kf0.y = bf2f(k8[1]);
        kf0.z = bf2f(k8[2]); kf0.w = bf2f(k8[3]);
        kf1.x = bf2f(k8[4]); kf1.y = bf2f(k8[5]);
        kf1.z = bf2f(k8[6]); kf1.w = bf2f(k8[7]);
        qf0.x = bf2f(q8[0]) * scale; qf0.y = bf2f(q8[1]) * scale;
        qf0.z = bf2f(q8[2]) * scale; qf0.w = bf2f(q8[3]) * scale;
        qf1.x = bf2f(q8[4]) * scale; qf1.y = bf2f(q8[5]) * scale;
        qf1.z = bf2f(q8[6]) * scale; qf1.w = bf2f(q8[7]) * scale;
        *(float4*)&Kn[i][ch]     = kf0;
        *(float4*)&Kn[i][ch + 4] = kf1;
        *(float4*)&Qn[i][ch]     = qf0;
        *(float4*)&Qn[i][ch + 4] = qf1;
    }
    __syncthreads();

    {
        const int i0 = (tid >> 4) * 2, j0 = (tid & 15) * 2;
        float wa[2][2] = {{0.f, 0.f}, {0.f, 0.f}};
        float pa[2][2] = {{0.f, 0.f}, {0.f, 0.f}};
        for (int k = 0; k < HEAD_DIM; k += 4) {
            float4 a0 = *(const float4*)&Kn[i0][k];
            float4 a1 = *(const float4*)&Kn[i0 + 1][k];
            float4 b0 = *(const float4*)&Kn[j0][k];
            float4 b1 = *(const float4*)&Kn[j0 + 1][k];
            float4 c0 = *(const float4*)&Qn[i0][k];
            float4 c1 = *(const float4*)&Qn[i0 + 1][k];
            const float* ap0 = (const float*)&a0;
            const float* ap1 = (const float*)&a1;
            const float* bp0 = (const float*)&b0;
            const float* bp1 = (const float*)&b1;
            const float* cp0 = (const float*)&c0;
            const float* cp1 = (const float*)&c1;
#pragma unroll
            for (int cc = 0; cc < 4; ++cc) {
                wa[0][0] = fmaf(ap0[cc], bp0[cc], wa[0][0]);
                wa[0][1] = fmaf(ap0[cc], bp1[cc], wa[0][1]);
                wa[1][0] = fmaf(ap1[cc], bp0[cc], wa[1][0]);
                wa[1][1] = fmaf(ap1[cc], bp1[cc], wa[1][1]);
                pa[0][0] = fmaf(cp0[cc], bp0[cc], pa[0][0]);
                pa[0][1] = fmaf(cp0[cc], bp1[cc], pa[0][1]);
                pa[1][0] = fmaf(cp1[cc], bp0[cc], pa[1][0]);
                pa[1][1] = fmaf(cp1[cc], bp1[cc], pa[1][1]);
            }
        }
#pragma unroll
        for (int di = 0; di < 2; ++di)
#pragma unroll
            for (int dj = 0; dj < 2; ++dj) {
                int i = i0 + di, j = j0 + dj;
                float rr = expf(fminf(cums[i] - cums[j], 0.f));
                Wm[i][j] = (j < i) ? betas[i] * rr * wa[di][dj] : 0.f;
                Pm[i][j] = (j <= i) ? rr * pa[di][dj] : 0.f;
            }
    }
    __syncthreads();

    {
        const int col = tid >> 3, tk = tid & 7;
        if (tk == 0) Tld[0][col] = (col == 0) ? 1.f : 0.f;
        for (int i = 1; i < CC; ++i) {
            float part = 0.f;
            for (int j = tk; j < i; j += 8)
                part = fmaf(Wm[i][j], Tld[j][col], part);
            part += __shfl_xor(part, 4);
            part += __shfl_xor(part, 2);
            part += __shfl_xor(part, 1);
            if (tk == 0) Tld[i][col] = ((i == col) ? 1.f : 0.f) - part;
        }
    }
    __syncthreads();

    // Trl = diag(rl) T ; PT = P @ T -> global (bf16)
    {
        const int i = tid >> 3, j0 = (tid & 7) * 4;
        const float r = rlS[i];
#pragma unroll
        for (int e = 0; e < 4; ++e)
            Trl[i][j0 + e] = Tld[i][j0 + e] * r;
        float4 accp = {0.f, 0.f, 0.f, 0.f};
        for (int m = 0; m < CC; ++m) {
            float pv = Pm[i][m];
            float4 tv = *(const float4*)&Tld[m][j0];
            accp.x = fmaf(pv, tv.x, accp.x);
            accp.y = fmaf(pv, tv.y, accp.y);
            accp.z = fmaf(pv, tv.z, accp.z);
            accp.w = fmaf(pv, tv.w, accp.w);
        }
        ushort4 pt4;
        pt4.x = f2bf(accp.x); pt4.y = f2bf(accp.y);
        pt4.z = f2bf(accp.z); pt4.w = f2bf(accp.w);
        *(ushort4*)(PTbuf + mb * (CC * CC) + tid * 4) = pt4;
    }
    __syncthreads();

    // K2[m][k] = sum_j Trl[j][m] * K[j][k]  -> bf16 global
    {
        const int m0 = tid >> 3;
        const int q  = (tid & 7) * 4;          // strided cols: q + 32*c
        float acc[4][4];
#pragma unroll
        for (int c = 0; c < 4; ++c)
#pragma unroll
            for (int e = 0; e < 4; ++e) acc[c][e] = 0.f;
        for (int j = 0; j < CC; ++j) {
            float t = Trl[j][m0];
#pragma unroll
            for (int c = 0; c < 4; ++c) {
                float4 a = *(const float4*)&Kn[j][q + 32 * c];
                acc[c][0] = fmaf(t, a.x, acc[c][0]);
                acc[c][1] = fmaf(t, a.y, acc[c][1]);
                acc[c][2] = fmaf(t, a.z, acc[c][2]);
                acc[c][3] = fmaf(t, a.w, acc[c][3]);
            }
        }
        unsigned short* kout =
            K2buf + mb * (CC * HEAD_DIM) + m0 * HEAD_DIM + q;
#pragma unroll
        for (int c = 0; c < 4; ++c) {
            ushort4 o4;
            o4.x = f2bf(acc[c][0]); o4.y = f2bf(acc[c][1]);
            o4.z = f2bf(acc[c][2]); o4.w = f2bf(acc[c][3]);
            *(ushort4*)(kout + 32 * c) = o4;
        }
    }
}

// ---------------------------------------------------------------------------
// GDN phase 2 — EXACT round-7 version (measured 262 us, 0 bank conflicts,
// 2 blocks/CU, LDS 49152). FROZEN: r6 (rp split) and r9 (NV=4) both
// regressed via bank conflicts / write amplification.
// ---------------------------------------------------------------------------
__global__ __launch_bounds__(256, 2) void gdn_p2(
    const float* __restrict__ vb, const unsigned short* __restrict__ qk_bf,
    const unsigned short* __restrict__ PTbuf,
    const unsigned short* __restrict__ K2buf, const float* __restrict__ lam_g,
    const float* __restrict__ bet_g, float* __restrict__ o)
{
    __shared__ unsigned short Kn[CC][128];
    __shared__ unsigned short Qn[CC][128];
    __shared__ unsigned short K2l[2][CC][128];
    __shared__ float PTl[2][CC][36];
    __shared__ float Sm[HEAD_DIM][NV + 2];
    __shared__ float Dl[CC][NV + 2];
    __shared__ float lamS[2][CC], betS[2][CC];

    const int tid = threadIdx.x;
    const int wv  = tid >> 6;
    const int ln  = tid & 63;
    const int h   = blockIdx.x >> 4;
    const int V0  = (blockIdx.x & 15) * NV;
    const int kh  = h >> 1;
    const float scale = 0.08838834764831845f;

    const int ri = tid >> 3;             // row 0..31
    const int rn = (tid & 3) * 2;        // col pair within NV=8
    const int hh = (tid >> 2) & 1;       // k-half owner (intra-pair 16B chunk)
    const int rx2 = ri & 3;              // read-side swizzle key

    const int fk = (tid >> 3) * 4;       // state: 4 k-rows
    const int sn = tid & 7;              // state: 1 col

    // DMA lane geometry (bf16 rows, 256B): 4 rows per wave-instr.
    const int drow = ln >> 4;            // row within 4-row group
    const int dc   = ln & 15;            // 16B chunk within row

#define DMA_KQ(T0)                                                            \
    {                                                                         \
        _Pragma("unroll")                                                     \
        for (int p = 0; p < 2; ++p) {                                         \
            const int i = p * 16 + wv * 4 + drow;                             \
            const int sc = 2 * ((dc >> 1) ^ (i & 3)) + (dc & 1);              \
            const unsigned short* sq = qk_bf + (size_t)((T0) + i) * 4096      \
                                       + kh * HEAD_DIM + sc * 8;              \
            __builtin_amdgcn_global_load_lds(                                 \
                (const __attribute__((address_space(1))) void*)(sq + K_TOTAL),\
                (__attribute__((address_space(3))) void*)                     \
                    &Kn[p * 16 + wv * 4][0], 16, 0, 0);                       \
            __builtin_amdgcn_global_load_lds(                                 \
                (const __attribute__((address_space(1))) void*)sq,            \
                (__attribute__((address_space(3))) void*)                     \
                    &Qn[p * 16 + wv * 4][0], 16, 0, 0);                       \
        }                                                                     \
    }

#define DMA_K2(MB, BUF)                                                       \
    {                                                                         \
        _Pragma("unroll")                                                     \
        for (int p = 0; p < 2; ++p) {                                         \
            const unsigned short* sk = K2buf + (MB) * (CC * HEAD_DIM)         \
                                       + p * 2048 + wv * 512 + ln * 8;        \
            __builtin_amdgcn_global_load_lds(                                 \
                (const __attribute__((address_space(1))) void*)sk,            \
                (__attribute__((address_space(3))) void*)                     \
                    &K2l[BUF][p * 16 + wv * 4][0], 16, 0, 0);                 \
        }                                                                     \
    }

#pragma unroll
    for (int c = 0; c < 4; ++c) Sm[fk + c][sn] = 0.f;

    // ---- prologue: chunk 0 ----
    DMA_KQ(0);
    DMA_K2((size_t)h, 0);
    {
        ushort4 pt0 = *(const ushort4*)(PTbuf + (size_t)h * (CC * CC) + tid * 4);
        float4 pf;
        pf.x = bf2f(pt0.x); pf.y = bf2f(pt0.y);
        pf.z = bf2f(pt0.z); pf.w = bf2f(pt0.w);
        *(float4*)&PTl[0][tid >> 3][(tid & 7) * 4] = pf;
        if (tid < CC) {
            lamS[0][tid] = lam_g[(size_t)h * CC + tid];
            betS[0][tid] = bet_g[(size_t)h * CC + tid];
        }
    }
    float2 vR = *(const float2*)(vb + (size_t)ri * V_TOTAL
                                 + h * HEAD_DIM + V0 + rn);

    int cur = 0;
    for (int cix = 0; cix < NCHUNK; ++cix) {
        const int t0 = cix * CC;
        __syncthreads();                       // bar A (drains DMAs)

        // ---- phase 1: r1/r2 ----
        const float lam = lamS[cur][ri];
        const float bet = betS[cur][ri];
        float r1x = 0.f, r1y = 0.f, r2x = 0.f, r2y = 0.f;
#pragma unroll
        for (int kk = 0; kk < 8; ++kk) {
            const int pc = (2 * (kk ^ rx2) + hh) * 8;   // physical ushort off
            const int cl = kk * 16 + hh * 8;            // logical k base
            u16x8 kv = *(const u16x8*)&Kn[ri][pc];
            u16x8 qv = *(const u16x8*)&Qn[ri][pc];
#pragma unroll
            for (int c8 = 0; c8 < 8; ++c8) {
                float kf = bf2f(kv[c8]);
                float qf = bf2f(qv[c8]);
                float2 s = *(const float2*)&Sm[cl + c8][rn];
                r1x = fmaf(kf, s.x, r1x);
                r1y = fmaf(kf, s.y, r1y);
                r2x = fmaf(qf, s.x, r2x);
                r2y = fmaf(qf, s.y, r2y);
            }
        }
        r1x += __shfl_xor(r1x, 4);
        r1y += __shfl_xor(r1y, 4);
        r2x += __shfl_xor(r2x, 4);
        r2y += __shfl_xor(r2y, 4);
        {
            float dlx = bet * (vR.x - lam * r1x);
            float dly = bet * (vR.y - lam * r1y);
            if (hh == 0) { Dl[ri][rn] = dlx; Dl[ri][rn + 1] = dly; }
        }
        const float lsc = lam * scale;
        float ox = r2x * lsc, oy = r2y * lsc;
        __syncthreads();                       // bar C (Dl visible; Kn/Qn dead)

        // ---- phase 2 ----
        const int nxt = cur ^ 1;
        ushort4 ptN; float lamN = 0.f, betN = 0.f; float2 vN;
        const int more = (cix + 1 < NCHUNK);
        if (more) {
            const int t0n = t0 + CC;
            const size_t mbn = (size_t)(cix + 1) * NUM_VH + h;
            DMA_KQ(t0n);
            DMA_K2(mbn, nxt);
            ptN = *(const ushort4*)(PTbuf + mbn * (CC * CC) + tid * 4);
            if (tid < CC) {
                lamN = lam_g[mbn * CC + tid];
                betN = bet_g[mbn * CC + tid];
            }
            vN = *(const float2*)(vb + (size_t)(t0n + ri) * V_TOTAL
                                  + h * HEAD_DIM + V0 + rn);
        }

        // O = lam*scale*r2 + PT @ Dl
        {
            for (int j = 0; j < CC; ++j) {
                float p = PTl[cur][ri][j];
                float2 d = *(const float2*)&Dl[j][rn];
                ox = fmaf(p, d.x, ox);
                oy = fmaf(p, d.y, oy);
            }
            if (hh == 0)
                *(float2*)(o + (size_t)(t0 + ri) * V_TOTAL + h * HEAD_DIM + V0 + rn)
                    = make_float2(ox, oy);
        }

        // S = lamL*S + K2^T @ Dl
        {
            const float lamL = lamS[cur][CC - 1];
            float s0 = lamL * Sm[fk + 0][sn];
            float s1 = lamL * Sm[fk + 1][sn];
            float s2 = lamL * Sm[fk + 2][sn];
            float s3 = lamL * Sm[fk + 3][sn];
            for (int j = 0; j < CC; ++j) {
                ushort4 kk = *(const ushort4*)&K2l[cur][j][fk];
                float d = Dl[j][sn];
                s0 = fmaf(bf2f(kk.x), d, s0);
                s1 = fmaf(bf2f(kk.y), d, s1);
                s2 = fmaf(bf2f(kk.z), d, s2);
                s3 = fmaf(bf2f(kk.w), d, s3);
            }
            Sm[fk + 0][sn] = s0;
            Sm[fk + 1][sn] = s1;
            Sm[fk + 2][sn] = s2;
            Sm[fk + 3][sn] = s3;
        }

        if (more) {
            float4 pf;
            pf.x = bf2f(ptN.x); pf.y = bf2f(ptN.y);
            pf.z = bf2f(ptN.z); pf.w = bf2f(ptN.w);
            *(float4*)&PTl[nxt][tid >> 3][(tid & 7) * 4] = pf;
            if (tid < CC) { lamS[nxt][tid] = lamN; betS[nxt][tid] = betN; }
            vR = vN;
        }
        cur = nxt;
    }
#undef DMA_KQ
#undef DMA_K2
}

// ---------------------------------------------------------------------------
// Gated RMSNorm, fused with bf16 output cast (writes ob_bf directly).
// ---------------------------------------------------------------------------
__global__ __launch_bounds__(64) void rmsnorm_gate_kernel(
    const float* __restrict__ o, const float* __restrict__ z,
    const float* __restrict__ nw, unsigned short* __restrict__ ob_bf)
{
    const int row = blockIdx.x;
    const float* p = o + (size_t)row * HEAD_DIM;
    const float* zp = z + (size_t)row * HEAD_DIM;
    const int lane = threadIdx.x;
    float2 v = *(const float2*)(p + lane * 2);
    float s = v.x * v.x + v.y * v.y;
    for (int off = 32; off > 0; off >>= 1) s += __shfl_down(s, off);
    s = __shfl(s, 0);
    float inv = rsqrtf(s * (1.f / HEAD_DIM) + EPS_F);
    float2 zv = *(const float2*)(zp + lane * 2);
    float2 wv = *(const float2*)(nw + lane * 2);
    v.x = v.x * inv * wv.x * (zv.x / (1.f + expf(-zv.x)));
    v.y = v.y * inv * wv.y * (zv.y / (1.f + expf(-zv.y)));
    unsigned short* q = ob_bf + (size_t)row * HEAD_DIM + lane * 2;
    q[0] = f2bf(v.x);
    q[1] = f2bf(v.y);
}

// ---------------------------------------------------------------------------
// Workspace layout (floats), audited against launch order:
//   mixed_bf [0, 8388608)          QKV GEMM bf16 out; dead after conv kernels
//   ob       [0, 8388608)          p2 output (mixed_bf dead by then)
//   PTbuf    [8388608, 9437184)    bf16, p1 out; dead after p2
//   ob_bf    [8388608, 9437184)    rmsnorm out (PTbuf dead)
//   K2buf    [9437184, 13631488)   bf16; dead after p2
//   lam_b    [13631488, 13697024), bet_b [13697024, 13762560)
//   hs_bf    [16777216, 17825792)  dead after GEMMs
//   Wqkv_bf  [18874368, 23068672)  dead after QKV GEMM
//   vb       [16777216, 25165824)  conv_v out (overwrites hs_bf/Wqkv_bf)
//   qk_bf    [25165824, 29360128)  convqk_l2 out (Wz_bf dead by then)
//   Wz_bf    [27262976, 31457280)  dead after z GEMM
//   Wab      [27262976, 27394048), ab [27394048, 27525120)  (dead early)
//   zb       [33554432, 41943040)  live until rmsnorm
//   Wout_bf  [37748736, 41943040)  written after rmsnorm (overlaps zb)
//   gb       [41943040, 42008576), bb [42008576, 42074112)
// ---------------------------------------------------------------------------
extern "C" void kernel_launch(void* const* d_in, const int* in_sizes, int n_in,
                              void* d_out, int out_size, void* d_ws,
                              size_t ws_size, hipStream_t stream)
{
    const float* hs    = (const float*)d_in[0];
    const float* Wqkv  = (const float*)d_in[1];
    const float* Wz    = (const float*)d_in[2];
    const float* Wa    = (const float*)d_in[3];
    const float* Wb    = (const float*)d_in[4];
    const float* cw    = (const float*)d_in[5];
    const float* Wout  = (const float*)d_in[6];
    const float* nw    = (const float*)d_in[7];
    const float* A_log = (const float*)d_in[8];
    const float* dtb   = (const float*)d_in[9];
    float* out = (float*)d_out;

    float* F     = (float*)d_ws;
    unsigned short* mixed_bf = (unsigned short*)F;
    float* ob    = F;
    unsigned short* PTbuf = (unsigned short*)(F + (size_t)8388608);
    unsigned short* ob_bf = (unsigned short*)(F + (size_t)8388608);
    unsigned short* K2buf = (unsigned short*)(F + (size_t)9437184);
    float* lam_b = F + (size_t)13631488;
    float* bet_b = F + (size_t)13697024;
    unsigned short* hs_bf   = (unsigned short*)(F + (size_t)16777216);
    unsigned short* Wqkv_bf = (unsigned short*)(F + (size_t)18874368);
    float* vb = F + (size_t)16777216;
    unsigned short* qk_bf = (unsigned short*)(F + (size_t)25165824);
    unsigned short* Wz_bf   = (unsigned short*)(F + (size_t)27262976);
    float* Wab = F + (size_t)27262976;
    float* ab  = F + (size_t)27394048;
    float* zb  = F + (size_t)33554432;
    unsigned short* Wout_bf = (unsigned short*)(F + (size_t)37748736);
    float* gb = F + (size_t)41943040;
    float* bb = F + (size_t)42008576;

    cast3_kernel<<<7340032 / 256, 256, 0, stream>>>(
        hs, Wqkv, Wz, hs_bf, Wqkv_bf, Wz_bf);
    gemm_bt_bf16_o16<<<dim3(QKV_TOTAL / 128, T_SEQ / 128), 256, 0, stream>>>(
        hs_bf, Wqkv_bf, mixed_bf, T_SEQ, QKV_TOTAL, HIDDEN_D);
    gemm_bt_bf16<<<dim3(V_TOTAL / 128, T_SEQ / 128), 256, 0, stream>>>(
        hs_bf, Wz_bf, zb, T_SEQ, V_TOTAL, HIDDEN_D);
    concat_ab_kernel<<<32768 / 256, 256, 0, stream>>>(Wa, Wb, Wab);
    gemm_nt_64<<<dim3(1, T_SEQ / 64), 256, 0, stream>>>(
        hs, Wab, ab, T_SEQ, 64, HIDDEN_D);
    gating_finalize_kernel<<<(T_SEQ * NUM_VH) / 256, 256, 0, stream>>>(
        ab, A_log, dtb, gb, bb);
    conv_v_kernel<<<(T_SEQ * V_TOTAL) / 256, 256, 0, stream>>>(
        mixed_bf, cw, vb);
    convqk_l2_kernel<<<T_SEQ * 32, 64, 0, stream>>>(mixed_bf, cw, qk_bf);
    gdn_p1<<<dim3(NUM_VH, NCHUNK), 256, 0, stream>>>(
        qk_bf, gb, bb, PTbuf, K2buf, lam_b, bet_b);
    gdn_p2<<<NUM_VH * (HEAD_DIM / NV), 256, 0, stream>>>(
        vb, qk_bf, PTbuf, K2buf, lam_b, bet_b, ob);
    rmsnorm_gate_kernel<<<T_SEQ * NUM_VH, 64, 0, stream>>>(ob, zb, nw, ob_bf);
    cast_bf16_kernel<<<2097152 / 256, 256, 0, stream>>>(Wout, Wout_bf, 2097152);
    gemm_bt_bf16<<<dim3(HIDDEN_D / 128, T_SEQ / 128), 256, 0, stream>>>(
        ob_bf, Wout_bf, out, T_SEQ, HIDDEN_D, V_TOTAL);
}